// Round 2
// baseline (9807.944 us; speedup 1.0000x reference)
//
#include <hip/hip_runtime.h>

#define HID 256

__device__ __forceinline__ float siluf(float x) { return x / (1.f + __expf(-x)); }
__device__ __forceinline__ float geluf(float x) {
    return 0.5f * x * (1.f + tanhf(0.7978845608028654f * (x + 0.044715f * x * x * x)));
}

// ---------------- generic fp32 tiled GEMM: C = act(preact(A) @ B + bias) [+C] ----------
// 128x128 tile, BK=16, 256 threads, 8x8 per thread. N%128==0, K%16==0 required.
__global__ __launch_bounds__(256) void gemm128(
    const float* __restrict__ A, int lda,
    const float* __restrict__ B, int ldb,
    float* __restrict__ C, int ldc,
    int M, int N, int K,
    const float* __restrict__ bias, int preact, int act, int addC)
{
    __shared__ float As[16][132];
    __shared__ float Bs[16][132];
    const int tid = threadIdx.x;
    const int tx = tid & 15, ty = tid >> 4;
    const int row0 = blockIdx.y * 128, col0 = blockIdx.x * 128;

    float acc[8][8];
#pragma unroll
    for (int i = 0; i < 8; ++i)
#pragma unroll
        for (int j = 0; j < 8; ++j) acc[i][j] = 0.f;

    const int ar = tid >> 1, ac = (tid & 1) * 8;
    const int br = tid >> 4, bc = (tid & 15) * 8;

    for (int k0 = 0; k0 < K; k0 += 16) {
        float a0x, a0y, a0z, a0w, a1x, a1y, a1z, a1w;
        int gr = row0 + ar;
        if (gr < M) {
            const float* pA = A + (size_t)gr * lda + k0 + ac;
            float4 v0 = *(const float4*)pA;
            float4 v1 = *(const float4*)(pA + 4);
            a0x = v0.x; a0y = v0.y; a0z = v0.z; a0w = v0.w;
            a1x = v1.x; a1y = v1.y; a1z = v1.z; a1w = v1.w;
        } else {
            a0x = a0y = a0z = a0w = a1x = a1y = a1z = a1w = 0.f;
        }
        if (preact == 1) {
            a0x = siluf(a0x); a0y = siluf(a0y); a0z = siluf(a0z); a0w = siluf(a0w);
            a1x = siluf(a1x); a1y = siluf(a1y); a1z = siluf(a1z); a1w = siluf(a1w);
        }
        const float* pB = B + (size_t)(k0 + br) * ldb + col0 + bc;
        float4 b0 = *(const float4*)pB;
        float4 b1 = *(const float4*)(pB + 4);

        __syncthreads();
        As[ac + 0][ar] = a0x; As[ac + 1][ar] = a0y; As[ac + 2][ar] = a0z; As[ac + 3][ar] = a0w;
        As[ac + 4][ar] = a1x; As[ac + 5][ar] = a1y; As[ac + 6][ar] = a1z; As[ac + 7][ar] = a1w;
        *(float4*)&Bs[br][bc] = b0;
        *(float4*)&Bs[br][bc + 4] = b1;
        __syncthreads();

#pragma unroll
        for (int k = 0; k < 16; ++k) {
            float4 av0 = *(float4*)&As[k][ty * 8];
            float4 av1 = *(float4*)&As[k][ty * 8 + 4];
            float4 bv0 = *(float4*)&Bs[k][tx * 8];
            float4 bv1 = *(float4*)&Bs[k][tx * 8 + 4];
            float a[8] = {av0.x, av0.y, av0.z, av0.w, av1.x, av1.y, av1.z, av1.w};
            float b[8] = {bv0.x, bv0.y, bv0.z, bv0.w, bv1.x, bv1.y, bv1.z, bv1.w};
#pragma unroll
            for (int i = 0; i < 8; ++i)
#pragma unroll
                for (int j = 0; j < 8; ++j)
                    acc[i][j] = fmaf(a[i], b[j], acc[i][j]);
        }
    }

#pragma unroll
    for (int i = 0; i < 8; ++i) {
        int gr = row0 + ty * 8 + i;
        if (gr >= M) break;
        float* pC = C + (size_t)gr * ldc + col0 + tx * 8;
#pragma unroll
        for (int j = 0; j < 8; ++j) {
            float v = acc[i][j];
            if (bias) v += bias[col0 + tx * 8 + j];
            if (act == 1) v = siluf(v);
            else if (act == 2) v = geluf(v);
            if (addC) v += pC[j];
            pC[j] = v;
        }
    }
}

// ---------------- LN + modulate: Y = ln(X)*(1+scale)+shift ------------------------------
__global__ __launch_bounds__(256) void k_ln_mod(
    const float* __restrict__ X, float* __restrict__ Y, int M,
    const float* __restrict__ ssb, int ldss, int shoff, int scoff)
{
    int row = (blockIdx.x << 2) + (threadIdx.x >> 6);
    if (row >= M) return;
    int lane = threadIdx.x & 63;
    const float* xr = X + (size_t)row * HID + lane * 4;
    float x0 = xr[0], x1 = xr[1], x2 = xr[2], x3 = xr[3];
    float s = x0 + x1 + x2 + x3;
    float q = x0 * x0 + x1 * x1 + x2 * x2 + x3 * x3;
#pragma unroll
    for (int o = 32; o; o >>= 1) { s += __shfl_xor(s, o, 64); q += __shfl_xor(q, o, 64); }
    float m = s * (1.f / HID);
    float r = rsqrtf(q * (1.f / HID) - m * m + 1e-6f);
    const float* sp = ssb + (size_t)row * ldss;
    const float* sh = sp + shoff + lane * 4;
    const float* sc = sp + scoff + lane * 4;
    float* yr = Y + (size_t)row * HID + lane * 4;
    yr[0] = (x0 - m) * r * (1.f + sc[0]) + sh[0];
    yr[1] = (x1 - m) * r * (1.f + sc[1]) + sh[1];
    yr[2] = (x2 - m) * r * (1.f + sc[2]) + sh[2];
    yr[3] = (x3 - m) * r * (1.f + sc[3]) + sh[3];
}

// ----- Y = modulate( ln(A + gate.*Bv) [*g + b], shift, scale ) --------------------------
__global__ __launch_bounds__(256) void k_ln_mod_resid(
    const float* __restrict__ A, const float* __restrict__ Bv, float* __restrict__ Y, int M,
    const float* __restrict__ gb, int ldg, int goff,
    const float* __restrict__ ssb, int ldss, int shoff, int scoff,
    const float* __restrict__ gw, const float* __restrict__ bw)
{
    int row = (blockIdx.x << 2) + (threadIdx.x >> 6);
    if (row >= M) return;
    int lane = threadIdx.x & 63;
    const float* ar = A + (size_t)row * HID + lane * 4;
    const float* br = Bv + (size_t)row * HID + lane * 4;
    const float* gp = gb + (size_t)row * ldg + goff + lane * 4;
    float t0 = ar[0] + gp[0] * br[0];
    float t1 = ar[1] + gp[1] * br[1];
    float t2 = ar[2] + gp[2] * br[2];
    float t3 = ar[3] + gp[3] * br[3];
    float s = t0 + t1 + t2 + t3;
    float q = t0 * t0 + t1 * t1 + t2 * t2 + t3 * t3;
#pragma unroll
    for (int o = 32; o; o >>= 1) { s += __shfl_xor(s, o, 64); q += __shfl_xor(q, o, 64); }
    float m = s * (1.f / HID);
    float r = rsqrtf(q * (1.f / HID) - m * m + 1e-6f);
    float n0 = (t0 - m) * r, n1 = (t1 - m) * r, n2 = (t2 - m) * r, n3 = (t3 - m) * r;
    if (gw) {
        const float* g4 = gw + lane * 4;
        const float* b4 = bw + lane * 4;
        n0 = n0 * g4[0] + b4[0]; n1 = n1 * g4[1] + b4[1];
        n2 = n2 * g4[2] + b4[2]; n3 = n3 * g4[3] + b4[3];
    }
    const float* sp = ssb + (size_t)row * ldss;
    const float* sh = sp + shoff + lane * 4;
    const float* sc = sp + scoff + lane * 4;
    float* yr = Y + (size_t)row * HID + lane * 4;
    yr[0] = n0 * (1.f + sc[0]) + sh[0];
    yr[1] = n1 * (1.f + sc[1]) + sh[1];
    yr[2] = n2 * (1.f + sc[2]) + sh[2];
    yr[3] = n3 * (1.f + sc[3]) + sh[3];
}

// ---------------- attention ------------------------------------------------------------
__device__ __forceinline__ unsigned fkey(float f) {
    unsigned u = __float_as_uint(f);
    return (u & 0x80000000u) ? ~u : (u | 0x80000000u);
}
__device__ __forceinline__ float funkey(unsigned k) {
    return (k & 0x80000000u) ? __uint_as_float(k & 0x7FFFFFFFu) : __uint_as_float(~k);
}

// one block per (chunk-local) edge; src/tgt/alpha pre-offset to chunk start
__global__ __launch_bounds__(256) void attn_alpha_k(
    const float* __restrict__ qkv, const float* __restrict__ ea,
    const int* __restrict__ src, const int* __restrict__ tgt,
    float* __restrict__ alpha, unsigned* __restrict__ amaxU)
{
    int e = blockIdx.x;
    int t = threadIdx.x;
    int h = t >> 5, d = t & 31;
    int s = src[e], g = tgt[e];
    float qv = qkv[(size_t)s * 768 + h * 32 + d];
    float kv = qkv[(size_t)g * 768 + 256 + h * 32 + d];
    float wv = ea[(size_t)e * 256 + t];
    float v = qv * kv * wv;
#pragma unroll
    for (int o = 16; o; o >>= 1) v += __shfl_xor(v, o, 32);
    if (d == 0) {
        float a = v * 0.17677669529663687f;  // 1/sqrt(32)
        alpha[(size_t)e * 8 + h] = a;
        atomicMax(&amaxU[(size_t)g * 8 + h], fkey(a));
    }
}

__global__ __launch_bounds__(256) void attn_exp_k(
    float* __restrict__ alpha, const unsigned* __restrict__ amaxU,
    float* __restrict__ denom, const int* __restrict__ tgt, int EH)
{
    int i = blockIdx.x * 256 + threadIdx.x;
    if (i >= EH) return;
    int e = i >> 3, h = i & 7;
    int g = tgt[e];
    float m = funkey(amaxU[(size_t)g * 8 + h]);
    float ex = __expf(alpha[i] - m);
    alpha[i] = ex;
    atomicAdd(&denom[(size_t)g * 8 + h], ex);
}

// chunk-local: e1/alpha/tgt pre-offset
__global__ __launch_bounds__(256) void attn_msg_k(
    const float* __restrict__ qkv, const float* __restrict__ e1,
    const float* __restrict__ alpha, const float* __restrict__ denom,
    const int* __restrict__ tgt, float* __restrict__ hattn, long long EC)
{
    long long i = (long long)blockIdx.x * 256 + threadIdx.x;
    if (i >= EC) return;
    long long e = i >> 8;
    int c = (int)(i & 255);
    int h = c >> 5;
    int g = tgt[e];
    float w = alpha[e * 8 + h] / denom[(size_t)g * 8 + h];
    float val = qkv[(size_t)g * 768 + 512 + c] * e1[i] * w;
    atomicAdd(&hattn[(size_t)g * 256 + c], val);
}

// ---------------- small elementwise kernels --------------------------------------------
__global__ __launch_bounds__(256) void k_gsum(
    const float* __restrict__ hattn, const int* __restrict__ src, const int* __restrict__ tgt,
    float* __restrict__ g, long long cnt)
{
    long long i = (long long)blockIdx.x * 256 + threadIdx.x;
    if (i >= cnt) return;
    long long e = i >> 8;
    int c = (int)(i & 255);
    g[i] = hattn[(size_t)src[e] * 256 + c] + hattn[(size_t)tgt[e] * 256 + c];
}

__global__ __launch_bounds__(256) void k_swiglu(
    const float* __restrict__ h12, float* __restrict__ c, long long cnt)
{
    long long i = (long long)blockIdx.x * 256 + threadIdx.x;
    if (i >= cnt) return;
    long long r = i >> 10;
    int j = (int)(i & 1023);
    float a = h12[r * 2048 + j];
    float b = h12[r * 2048 + 1024 + j];
    c[i] = siluf(a) * b;
}

// out = [eae +] h2 + g[row,goff+c]*f
__global__ __launch_bounds__(256) void k_final(
    const float* __restrict__ eae, const float* __restrict__ h2, const float* __restrict__ f,
    const float* __restrict__ g, int ldg, int goff, float* __restrict__ out, long long cnt)
{
    long long i = (long long)blockIdx.x * 256 + threadIdx.x;
    if (i >= cnt) return;
    long long r = i >> 8;
    int c = (int)(i & 255);
    float v = h2[i] + g[r * (size_t)ldg + goff + c] * f[i];
    if (eae) v += eae[i];
    out[i] = v;
}

// ---------------------------------------------------------------------------------------
static inline void gemm(hipStream_t st, const float* A, int lda, const float* B, int ldb,
                        float* C, int ldc, int M, int N, int K,
                        const float* bias, int preact, int act, int addC)
{
    dim3 g(N / 128, (M + 127) / 128);
    hipLaunchKernelGGL(gemm128, g, dim3(256), 0, st, A, lda, B, ldb, C, ldc, M, N, K,
                       bias, preact, act, addC);
}

extern "C" void kernel_launch(void* const* d_in, const int* in_sizes, int n_in,
                              void* d_out, int out_size, void* d_ws, size_t ws_size,
                              hipStream_t stream)
{
    const int Nn = in_sizes[0];
    const int E = in_sizes[3] / HID;

    const float* x        = (const float*)d_in[1];
    const float* t_emb_h  = (const float*)d_in[2];
    const float* edge_attr= (const float*)d_in[3];
    const int*   eidx     = (const int*)d_in[4];
    const float* t_emb_e  = (const float*)d_in[5];
    const float* dist     = (const float*)d_in[6];
    const float* W_ee     = (const float*)d_in[7];
    const float* b_ee     = (const float*)d_in[8];
    const float* W_ad     = (const float*)d_in[9];
    const float* b_ad     = (const float*)d_in[10];
    const float* W_ade    = (const float*)d_in[11];
    const float* b_ade    = (const float*)d_in[12];
    const float* W_qkv    = (const float*)d_in[13];
    const float* W_e0     = (const float*)d_in[14];
    const float* W_e1     = (const float*)d_in[15];
    const float* W_n2e    = (const float*)d_in[16];
    const float* b_n2e    = (const float*)d_in[17];
    const float* g_ln     = (const float*)d_in[18];
    const float* b_ln     = (const float*)d_in[19];
    const float* W_f12    = (const float*)d_in[20];
    const float* W_fout   = (const float*)d_in[21];
    const float* W_fe12   = (const float*)d_in[22];
    const float* W_feout  = (const float*)d_in[23];

    const int* src = eidx;
    const int* tgt = eidx + E;

    float* outN = (float*)d_out;
    float* outE = (float*)d_out + (size_t)Nn * 256;   // also stores edge_attr_e (prev_edge_attr)

    // ---- persistent workspace (small): 46.7 MB at N=10000, E=160000 ----
    char* W = (char*)d_ws;
    size_t off = 0;
    auto alloc = [&](size_t bytes) -> size_t {
        size_t o = off; off += (bytes + 255) & ~(size_t)255; return o;
    };
    float*    alpha = (float*)(W + alloc((size_t)E * 8 * 4));
    unsigned* amaxU = (unsigned*)(W + alloc((size_t)Nn * 8 * 4));
    float*    den   = (float*)(W + alloc((size_t)Nn * 8 * 4));
    float*    hat   = (float*)(W + alloc((size_t)Nn * 256 * 4));
    float*    qkv   = (float*)(W + alloc((size_t)Nn * 768 * 4));

    char* pool = W + off;
    size_t poolB = (ws_size > off) ? (ws_size - off) : 0;
    auto chunkRows = [&](size_t perRowFloats, int total) -> int {
        long c = (long)(poolB / (perRowFloats * 4));
        c = (c / 256) * 256;
        if (c < 256) c = 256;
        if (c > total) c = (long)total;
        return (int)c;
    };

    hipMemsetAsync(amaxU, 0, (size_t)Nn * 8 * 4, stream);
    hipMemsetAsync(den, 0, (size_t)Nn * 8 * 4, stream);
    hipMemsetAsync(hat, 0, (size_t)Nn * 256 * 4, stream);

    // ---- phase 1: node pre (chunked): ms = silu(t)@W_ad[:,0:512]+b; xm = mod(ln(x)); qkv ----
    {
        int C = chunkRows(512 + 256, Nn);
        float* msc = (float*)pool;
        float* xmc = msc + (size_t)C * 512;
        for (int s = 0; s < Nn; s += C) {
            int cc = (Nn - s < C) ? (Nn - s) : C;
            gemm(stream, t_emb_h + (size_t)s * 256, 256, W_ad, 1536, msc, 512,
                 cc, 512, 256, b_ad, 1, 0, 0);
            hipLaunchKernelGGL(k_ln_mod, dim3((cc + 3) / 4), dim3(256), 0, stream,
                               x + (size_t)s * 256, xmc, cc, msc, 512, 0, 256);
            gemm(stream, xmc, 256, W_qkv, 768, qkv + (size_t)s * 768, 768,
                 cc, 768, 256, nullptr, 0, 0, 0);
        }
    }

    // ---- phase 2: edge pre (chunked): eae -> outE; e_mod; ea=gelu(e_mod@W_e0); alpha ----
    {
        int C = chunkRows(512 + 256 + 256, E);
        float* emsc  = (float*)pool;
        float* emodc = emsc + (size_t)C * 512;
        float* eac   = emodc + (size_t)C * 256;
        for (int s = 0; s < E; s += C) {
            int cc = (E - s < C) ? (E - s) : C;
            float* eaeC = outE + (size_t)s * 256;
            gemm(stream, edge_attr + (size_t)s * 256, 256, W_ee, 256, eaeC, 256,
                 cc, 256, 256, b_ee, 0, 0, 0);
            gemm(stream, dist + (size_t)s * 128, 128, W_ee + 256 * 256, 256, eaeC, 256,
                 cc, 256, 128, nullptr, 0, 0, 1);
            gemm(stream, t_emb_e + (size_t)s * 256, 256, W_ade, 1536, emsc, 512,
                 cc, 512, 256, b_ade, 1, 0, 0);
            hipLaunchKernelGGL(k_ln_mod, dim3((cc + 3) / 4), dim3(256), 0, stream,
                               eaeC, emodc, cc, emsc, 512, 0, 256);
            gemm(stream, emodc, 256, W_e0, 256, eac, 256, cc, 256, 256, nullptr, 0, 2, 0);
            hipLaunchKernelGGL(attn_alpha_k, dim3(cc), dim3(256), 0, stream,
                               qkv, eac, src + s, tgt + s, alpha + (size_t)s * 8, amaxU);
        }
    }

    // ---- phase 3: exp + denom ----
    hipLaunchKernelGGL(attn_exp_k, dim3((E * 8 + 255) / 256), dim3(256), 0, stream,
                       alpha, amaxU, den, tgt, E * 8);

    // ---- phase 4: message pass (chunked, recompute e_mod, e1) ----
    {
        int C = chunkRows(512 + 256 + 256, E);
        float* emsc  = (float*)pool;
        float* emodc = emsc + (size_t)C * 512;
        float* e1c   = emodc + (size_t)C * 256;
        for (int s = 0; s < E; s += C) {
            int cc = (E - s < C) ? (E - s) : C;
            const float* eaeC = outE + (size_t)s * 256;
            gemm(stream, t_emb_e + (size_t)s * 256, 256, W_ade, 1536, emsc, 512,
                 cc, 512, 256, b_ade, 1, 0, 0);
            hipLaunchKernelGGL(k_ln_mod, dim3((cc + 3) / 4), dim3(256), 0, stream,
                               eaeC, emodc, cc, emsc, 512, 0, 256);
            gemm(stream, emodc, 256, W_e1, 256, e1c, 256, cc, 256, 256, nullptr, 0, 0, 0);
            long long cnt = (long long)cc * 256;
            hipLaunchKernelGGL(attn_msg_k, dim3((unsigned)((cnt + 255) / 256)), dim3(256),
                               0, stream, qkv, e1c, alpha + (size_t)s * 8, den, tgt + s,
                               hat, cnt);
        }
    }

    // ---- phase 5: node finish (chunked): ad2 = silu(t)@W_ad[:,512:]; resid+LN+mod; FFN ----
    {
        int C = chunkRows(1024 + 256 + 2048 + 1024 + 256, Nn);
        float* ad2c = (float*)pool;
        float* h2c  = ad2c + (size_t)C * 1024;
        float* h12c = h2c + (size_t)C * 256;
        float* cc_  = h12c + (size_t)C * 2048;
        float* fc   = cc_ + (size_t)C * 1024;
        for (int s = 0; s < Nn; s += C) {
            int cc = (Nn - s < C) ? (Nn - s) : C;
            gemm(stream, t_emb_h + (size_t)s * 256, 256, W_ad + 512, 1536, ad2c, 1024,
                 cc, 1024, 256, b_ad + 512, 1, 0, 0);
            hipLaunchKernelGGL(k_ln_mod_resid, dim3((cc + 3) / 4), dim3(256), 0, stream,
                               x + (size_t)s * 256, hat + (size_t)s * 256, h2c, cc,
                               ad2c, 1024, 0, ad2c, 1024, 256, 512, g_ln, b_ln);
            gemm(stream, h2c, 256, W_f12, 2048, h12c, 2048, cc, 2048, 256, nullptr, 0, 0, 0);
            long long scnt = (long long)cc * 1024;
            hipLaunchKernelGGL(k_swiglu, dim3((unsigned)((scnt + 255) / 256)), dim3(256),
                               0, stream, h12c, cc_, scnt);
            gemm(stream, cc_, 1024, W_fout, 256, fc, 256, cc, 256, 1024, nullptr, 0, 0, 0);
            long long cnt = (long long)cc * 256;
            hipLaunchKernelGGL(k_final, dim3((unsigned)((cnt + 255) / 256)), dim3(256), 0, stream,
                               (const float*)nullptr, h2c, fc, ad2c, 1024, 768,
                               outN + (size_t)s * 256, cnt);
        }
    }

    // ---- phase 6: edge finish (chunked) ----
    {
        int C = chunkRows(256 + 256 + 1024 + 256 + 2048 + 1024 + 256, E);
        float* gsumc = (float*)pool;
        float* hepc  = gsumc + (size_t)C * 256;
        float* em2c  = hepc + (size_t)C * 256;
        float* h2c   = em2c + (size_t)C * 1024;
        float* h12c  = h2c + (size_t)C * 256;
        float* cc_   = h12c + (size_t)C * 2048;
        float* fc    = cc_ + (size_t)C * 1024;
        for (int s = 0; s < E; s += C) {
            int cc = (E - s < C) ? (E - s) : C;
            long long cnt = (long long)cc * 256;
            hipLaunchKernelGGL(k_gsum, dim3((unsigned)((cnt + 255) / 256)), dim3(256), 0, stream,
                               hat, src + s, tgt + s, gsumc, cnt);
            gemm(stream, gsumc, 256, W_n2e, 256, hepc, 256, cc, 256, 256, b_n2e, 0, 0, 0);
            gemm(stream, t_emb_e + (size_t)s * 256, 256, W_ade + 512, 1536, em2c, 1024,
                 cc, 1024, 256, b_ade + 512, 1, 0, 0);
            hipLaunchKernelGGL(k_ln_mod_resid, dim3((cc + 3) / 4), dim3(256), 0, stream,
                               edge_attr + (size_t)s * 256, hepc, h2c, cc,
                               em2c, 1024, 0, em2c, 1024, 256, 512, nullptr, nullptr);
            gemm(stream, h2c, 256, W_fe12, 2048, h12c, 2048, cc, 2048, 256, nullptr, 0, 0, 0);
            long long scnt = (long long)cc * 1024;
            hipLaunchKernelGGL(k_swiglu, dim3((unsigned)((scnt + 255) / 256)), dim3(256),
                               0, stream, h12c, cc_, scnt);
            gemm(stream, cc_, 1024, W_feout, 256, fc, 256, cc, 256, 1024, nullptr, 0, 0, 0);
            hipLaunchKernelGGL(k_final, dim3((unsigned)((cnt + 255) / 256)), dim3(256), 0, stream,
                               outE + (size_t)s * 256, h2c, fc, em2c, 1024, 768,
                               outE + (size_t)s * 256, cnt);
        }
    }
    (void)n_in; (void)out_size;
}

// Round 3
// 3365.739 us; speedup vs baseline: 2.9141x; 2.9141x over previous
//
#include <hip/hip_runtime.h>

#define HID 256

typedef unsigned short u16;
typedef __attribute__((ext_vector_type(8))) short bf16x8;
typedef __attribute__((ext_vector_type(4))) float f32x4;

__device__ __forceinline__ float siluf(float x) { return x / (1.f + __expf(-x)); }
__device__ __forceinline__ float geluf(float x) {
    return 0.5f * x * (1.f + tanhf(0.7978845608028654f * (x + 0.044715f * x * x * x)));
}
__device__ __forceinline__ u16 f2b(float x) {
    unsigned u = __float_as_uint(x);
    unsigned r = u + 0x7FFFu + ((u >> 16) & 1u);
    return (u16)(r >> 16);
}
__device__ __forceinline__ float b2f(u16 h) {
    return __uint_as_float(((unsigned)h) << 16);
}
__device__ __forceinline__ void gload16(const u16* g, u16* l) {
    __builtin_amdgcn_global_load_lds(
        (const __attribute__((address_space(1))) unsigned int*)g,
        (__attribute__((address_space(3))) unsigned int*)l, 16, 0, 0);
}
__device__ __forceinline__ int imin(int a, int b) { return a < b ? a : b; }

// ---------------- bf16 MFMA GEMM: C = act(A @ Bt^T + bias) [+C] -------------------------
// A: M x K bf16 row-major (lda elements). Bt: N x K bf16 row-major (ldb) = B transposed.
// 128x128 tile, BK=32, 256 threads (4 waves, 2x2 of 64x64 each), m97 2-phase structure.
// Requires N % 128 == 0, K % 32 == 0, lda/ldb % 8 == 0.
__global__ __launch_bounds__(256) void gemm_mfma(
    const u16* __restrict__ A, int lda,
    const u16* __restrict__ Bt, int ldb,
    void* __restrict__ Cv, int ldc,
    int M, int N, int K,
    const float* __restrict__ bias, int act, int addC, int obf16)
{
    __shared__ u16 lds[8192];   // [0..4095]: A tile [128][32]; [4096..8191]: Bt tile [128][32]

    const int tid  = threadIdx.x;
    const int lane = tid & 63;
    const int wave = tid >> 6;
    const int row0 = blockIdx.y * 128;
    const int col0 = blockIdx.x * 128;
    const int wm   = (wave >> 1) * 64;
    const int wn   = (wave & 1) * 64;

    f32x4 acc[4][4];
#pragma unroll
    for (int i = 0; i < 4; ++i)
#pragma unroll
        for (int j = 0; j < 4; ++j) acc[i][j] = (f32x4)0.0f;

    // staging: chunk c (0..7) = 16 rows; lane covers row c*16 + lane/4, k8 = (lane&3)*8
    const int c0 = wave, c1 = wave + 4;
    const int r0 = c0 * 16 + (lane >> 2), r1 = c1 * 16 + (lane >> 2);
    const int kc = (lane & 3) * 8;
    const u16* pa0 = A + (size_t)imin(row0 + r0, M - 1) * lda + kc;
    const u16* pa1 = A + (size_t)imin(row0 + r1, M - 1) * lda + kc;
    const u16* pb0 = Bt + (size_t)(col0 + r0) * ldb + kc;
    const u16* pb1 = Bt + (size_t)(col0 + r1) * ldb + kc;
    u16* la0 = &lds[c0 * 512];
    u16* la1 = &lds[c1 * 512];
    u16* lb0 = &lds[4096 + c0 * 512];
    u16* lb1 = &lds[4096 + c1 * 512];

    const int kb = (lane >> 4) * 8;   // k offset within BK for frags
    const int fr = lane & 15;

    for (int k0 = 0; k0 < K; k0 += 32) {
        gload16(pa0 + k0, la0);
        gload16(pa1 + k0, la1);
        gload16(pb0 + k0, lb0);
        gload16(pb1 + k0, lb1);
        __syncthreads();

        bf16x8 af[4], bfm[4];
#pragma unroll
        for (int i = 0; i < 4; ++i)
            af[i] = *(const bf16x8*)&lds[(wm + i * 16 + fr) * 32 + kb];
#pragma unroll
        for (int j = 0; j < 4; ++j)
            bfm[j] = *(const bf16x8*)&lds[4096 + (wn + j * 16 + fr) * 32 + kb];
#pragma unroll
        for (int i = 0; i < 4; ++i)
#pragma unroll
            for (int j = 0; j < 4; ++j)
                acc[i][j] = __builtin_amdgcn_mfma_f32_16x16x32_bf16(af[i], bfm[j], acc[i][j], 0, 0, 0);
        __syncthreads();
    }

    const int qr = (lane >> 4) * 4;
    float* Cf = (float*)Cv;
    u16*   Cb = (u16*)Cv;
#pragma unroll
    for (int i = 0; i < 4; ++i) {
#pragma unroll
        for (int r = 0; r < 4; ++r) {
            int grow = row0 + wm + i * 16 + qr + r;
            if (grow >= M) continue;
#pragma unroll
            for (int j = 0; j < 4; ++j) {
                int gcol = col0 + wn + j * 16 + fr;
                float v = acc[i][j][r];
                if (bias) v += bias[gcol];
                if (act == 2) v = geluf(v);
                else if (act == 1) v = siluf(v);
                size_t idx = (size_t)grow * ldc + gcol;
                if (obf16) {
                    Cb[idx] = f2b(v);
                } else {
                    if (addC) v += Cf[idx];
                    Cf[idx] = v;
                }
            }
        }
    }
}

// ---------------- weight transpose-convert: Wt[n*K+k] = bf16(W[k*N+n]) ------------------
__global__ __launch_bounds__(256) void k_wconv(
    const float* __restrict__ W, u16* __restrict__ Wt, int K, int N)
{
    int i = blockIdx.x * 256 + threadIdx.x;
    if (i >= K * N) return;
    int n = i / K, k = i - n * K;
    Wt[i] = f2b(W[(size_t)k * N + n]);
}

// ---------------- elementwise converters -----------------------------------------------
__global__ __launch_bounds__(256) void k_silu_b16(
    const float* __restrict__ src, u16* __restrict__ dst, long long n4)
{
    long long i = (long long)blockIdx.x * 256 + threadIdx.x;
    if (i >= n4) return;
    float4 v = ((const float4*)src)[i];
    ushort4 o;
    o.x = f2b(siluf(v.x)); o.y = f2b(siluf(v.y)); o.z = f2b(siluf(v.z)); o.w = f2b(siluf(v.w));
    ((ushort4*)dst)[i] = o;
}

__global__ __launch_bounds__(256) void k_f2b4(
    const float* __restrict__ src, u16* __restrict__ dst, long long n4)
{
    long long i = (long long)blockIdx.x * 256 + threadIdx.x;
    if (i >= n4) return;
    float4 v = ((const float4*)src)[i];
    ushort4 o;
    o.x = f2b(v.x); o.y = f2b(v.y); o.z = f2b(v.z); o.w = f2b(v.w);
    ((ushort4*)dst)[i] = o;
}

// ---------------- LN + modulate -> bf16 -------------------------------------------------
__global__ __launch_bounds__(256) void k_ln_mod_b16(
    const float* __restrict__ X, u16* __restrict__ Y, int M,
    const float* __restrict__ ssb, int ldss, int shoff, int scoff)
{
    int row = (blockIdx.x << 2) + (threadIdx.x >> 6);
    if (row >= M) return;
    int lane = threadIdx.x & 63;
    const float* xr = X + (size_t)row * HID + lane * 4;
    float x0 = xr[0], x1 = xr[1], x2 = xr[2], x3 = xr[3];
    float s = x0 + x1 + x2 + x3;
    float q = x0 * x0 + x1 * x1 + x2 * x2 + x3 * x3;
#pragma unroll
    for (int o = 32; o; o >>= 1) { s += __shfl_xor(s, o, 64); q += __shfl_xor(q, o, 64); }
    float m = s * (1.f / HID);
    float r = rsqrtf(q * (1.f / HID) - m * m + 1e-6f);
    const float* sp = ssb + (size_t)row * ldss;
    const float* sh = sp + shoff + lane * 4;
    const float* sc = sp + scoff + lane * 4;
    ushort4 o;
    o.x = f2b((x0 - m) * r * (1.f + sc[0]) + sh[0]);
    o.y = f2b((x1 - m) * r * (1.f + sc[1]) + sh[1]);
    o.z = f2b((x2 - m) * r * (1.f + sc[2]) + sh[2]);
    o.w = f2b((x3 - m) * r * (1.f + sc[3]) + sh[3]);
    ((ushort4*)(Y + (size_t)row * HID))[lane] = o;
}

// ----- Y(bf16) = modulate( ln(A + gate.*Bv) [*g + b], shift, scale ) --------------------
__global__ __launch_bounds__(256) void k_ln_mod_resid_b16(
    const float* __restrict__ A, const float* __restrict__ Bv, u16* __restrict__ Y, int M,
    const float* __restrict__ gb, int ldg, int goff,
    const float* __restrict__ ssb, int ldss, int shoff, int scoff,
    const float* __restrict__ gw, const float* __restrict__ bw)
{
    int row = (blockIdx.x << 2) + (threadIdx.x >> 6);
    if (row >= M) return;
    int lane = threadIdx.x & 63;
    const float* ar = A + (size_t)row * HID + lane * 4;
    const float* br = Bv + (size_t)row * HID + lane * 4;
    const float* gp = gb + (size_t)row * ldg + goff + lane * 4;
    float t0 = ar[0] + gp[0] * br[0];
    float t1 = ar[1] + gp[1] * br[1];
    float t2 = ar[2] + gp[2] * br[2];
    float t3 = ar[3] + gp[3] * br[3];
    float s = t0 + t1 + t2 + t3;
    float q = t0 * t0 + t1 * t1 + t2 * t2 + t3 * t3;
#pragma unroll
    for (int o = 32; o; o >>= 1) { s += __shfl_xor(s, o, 64); q += __shfl_xor(q, o, 64); }
    float m = s * (1.f / HID);
    float r = rsqrtf(q * (1.f / HID) - m * m + 1e-6f);
    float n0 = (t0 - m) * r, n1 = (t1 - m) * r, n2 = (t2 - m) * r, n3 = (t3 - m) * r;
    if (gw) {
        const float* g4 = gw + lane * 4;
        const float* b4 = bw + lane * 4;
        n0 = n0 * g4[0] + b4[0]; n1 = n1 * g4[1] + b4[1];
        n2 = n2 * g4[2] + b4[2]; n3 = n3 * g4[3] + b4[3];
    }
    const float* sp = ssb + (size_t)row * ldss;
    const float* sh = sp + shoff + lane * 4;
    const float* sc = sp + scoff + lane * 4;
    ushort4 o;
    o.x = f2b(n0 * (1.f + sc[0]) + sh[0]);
    o.y = f2b(n1 * (1.f + sc[1]) + sh[1]);
    o.z = f2b(n2 * (1.f + sc[2]) + sh[2]);
    o.w = f2b(n3 * (1.f + sc[3]) + sh[3]);
    ((ushort4*)(Y + (size_t)row * HID))[lane] = o;
}

// ---------------- attention ------------------------------------------------------------
__device__ __forceinline__ unsigned fkey(float f) {
    unsigned u = __float_as_uint(f);
    return (u & 0x80000000u) ? ~u : (u | 0x80000000u);
}
__device__ __forceinline__ float funkey(unsigned k) {
    return (k & 0x80000000u) ? __uint_as_float(k & 0x7FFFFFFFu) : __uint_as_float(~k);
}

__global__ __launch_bounds__(256) void attn_alpha_k(
    const u16* __restrict__ qkv, const float* __restrict__ ea,
    const int* __restrict__ src, const int* __restrict__ tgt,
    float* __restrict__ alpha, unsigned* __restrict__ amaxU)
{
    int e = blockIdx.x;
    int t = threadIdx.x;
    int h = t >> 5, d = t & 31;
    int s = src[e], g = tgt[e];
    float qv = b2f(qkv[(size_t)s * 768 + h * 32 + d]);
    float kv = b2f(qkv[(size_t)g * 768 + 256 + h * 32 + d]);
    float wv = ea[(size_t)e * 256 + t];
    float v = qv * kv * wv;
#pragma unroll
    for (int o = 16; o; o >>= 1) v += __shfl_xor(v, o, 32);
    if (d == 0) {
        float a = v * 0.17677669529663687f;  // 1/sqrt(32)
        alpha[(size_t)e * 8 + h] = a;
        atomicMax(&amaxU[(size_t)g * 8 + h], fkey(a));
    }
}

__global__ __launch_bounds__(256) void attn_exp_k(
    float* __restrict__ alpha, const unsigned* __restrict__ amaxU,
    float* __restrict__ denom, const int* __restrict__ tgt, int EH)
{
    int i = blockIdx.x * 256 + threadIdx.x;
    if (i >= EH) return;
    int e = i >> 3, h = i & 7;
    int g = tgt[e];
    float m = funkey(amaxU[(size_t)g * 8 + h]);
    float ex = __expf(alpha[i] - m);
    alpha[i] = ex;
    atomicAdd(&denom[(size_t)g * 8 + h], ex);
}

__global__ __launch_bounds__(256) void attn_msg_k(
    const u16* __restrict__ qkv, const float* __restrict__ e1,
    const float* __restrict__ alpha, const float* __restrict__ denom,
    const int* __restrict__ tgt, float* __restrict__ hattn, long long EC)
{
    long long i = (long long)blockIdx.x * 256 + threadIdx.x;
    if (i >= EC) return;
    long long e = i >> 8;
    int c = (int)(i & 255);
    int h = c >> 5;
    int g = tgt[e];
    float w = alpha[e * 8 + h] / denom[(size_t)g * 8 + h];
    float val = b2f(qkv[(size_t)g * 768 + 512 + c]) * e1[i] * w;
    atomicAdd(&hattn[(size_t)g * 256 + c], val);
}

// ---------------- small elementwise kernels --------------------------------------------
__global__ __launch_bounds__(256) void k_gsum_b16(
    const float* __restrict__ hattn, const int* __restrict__ src, const int* __restrict__ tgt,
    u16* __restrict__ g, long long cnt4)
{
    long long i = (long long)blockIdx.x * 256 + threadIdx.x;
    if (i >= cnt4) return;
    long long e = i >> 6;
    int c4 = (int)(i & 63) * 4;
    const float* ps = hattn + (size_t)src[e] * 256 + c4;
    const float* pt = hattn + (size_t)tgt[e] * 256 + c4;
    float4 a = *(const float4*)ps;
    float4 b = *(const float4*)pt;
    ushort4 o;
    o.x = f2b(a.x + b.x); o.y = f2b(a.y + b.y); o.z = f2b(a.z + b.z); o.w = f2b(a.w + b.w);
    ((ushort4*)g)[i] = o;
}

__global__ __launch_bounds__(256) void k_swiglu_b16(
    const u16* __restrict__ h12, u16* __restrict__ c, long long cnt4)
{
    long long i = (long long)blockIdx.x * 256 + threadIdx.x;
    if (i >= cnt4) return;
    long long r = i >> 8;
    int j4 = (int)(i & 255) * 4;
    ushort4 a = *(const ushort4*)&h12[r * 2048 + j4];
    ushort4 b = *(const ushort4*)&h12[r * 2048 + 1024 + j4];
    ushort4 o;
    o.x = f2b(siluf(b2f(a.x)) * b2f(b.x));
    o.y = f2b(siluf(b2f(a.y)) * b2f(b.y));
    o.z = f2b(siluf(b2f(a.z)) * b2f(b.z));
    o.w = f2b(siluf(b2f(a.w)) * b2f(b.w));
    ((ushort4*)c)[i] = o;
}

// out = [eae +] h2 + g[row,goff+c]*f   (h2 bf16, rest fp32)
__global__ __launch_bounds__(256) void k_final(
    const float* __restrict__ eae, const u16* __restrict__ h2, const float* __restrict__ f,
    const float* __restrict__ g, int ldg, int goff, float* __restrict__ out, long long cnt4)
{
    long long i = (long long)blockIdx.x * 256 + threadIdx.x;
    if (i >= cnt4) return;
    long long r = i >> 6;
    int c4 = (int)(i & 63) * 4;
    float4 fv = ((const float4*)f)[i];
    ushort4 hv = ((const ushort4*)h2)[i];
    const float* gp = g + r * (size_t)ldg + goff + c4;
    float4 gv = *(const float4*)gp;
    float4 o;
    o.x = b2f(hv.x) + gv.x * fv.x;
    o.y = b2f(hv.y) + gv.y * fv.y;
    o.z = b2f(hv.z) + gv.z * fv.z;
    o.w = b2f(hv.w) + gv.w * fv.w;
    if (eae) {
        float4 ev = ((const float4*)eae)[i];
        o.x += ev.x; o.y += ev.y; o.z += ev.z; o.w += ev.w;
    }
    ((float4*)out)[i] = o;
}

// ---------------------------------------------------------------------------------------
static inline void gemm(hipStream_t st, const u16* A, int lda, const u16* Bt, int ldb,
                        void* C, int ldc, int M, int N, int K,
                        const float* bias, int act, int addC, int obf16)
{
    dim3 g(N / 128, (M + 127) / 128);
    hipLaunchKernelGGL(gemm_mfma, g, dim3(256), 0, st, A, lda, Bt, ldb, C, ldc, M, N, K,
                       bias, act, addC, obf16);
}

extern "C" void kernel_launch(void* const* d_in, const int* in_sizes, int n_in,
                              void* d_out, int out_size, void* d_ws, size_t ws_size,
                              hipStream_t stream)
{
    const int Nn = in_sizes[0];
    const int E = in_sizes[3] / HID;

    const float* x        = (const float*)d_in[1];
    const float* t_emb_h  = (const float*)d_in[2];
    const float* edge_attr= (const float*)d_in[3];
    const int*   eidx     = (const int*)d_in[4];
    const float* t_emb_e  = (const float*)d_in[5];
    const float* dist     = (const float*)d_in[6];
    const float* W_ee     = (const float*)d_in[7];
    const float* b_ee     = (const float*)d_in[8];
    const float* W_ad     = (const float*)d_in[9];
    const float* b_ad     = (const float*)d_in[10];
    const float* W_ade    = (const float*)d_in[11];
    const float* b_ade    = (const float*)d_in[12];
    const float* W_qkv    = (const float*)d_in[13];
    const float* W_e0     = (const float*)d_in[14];
    const float* W_e1     = (const float*)d_in[15];
    const float* W_n2e    = (const float*)d_in[16];
    const float* b_n2e    = (const float*)d_in[17];
    const float* g_ln     = (const float*)d_in[18];
    const float* b_ln     = (const float*)d_in[19];
    const float* W_f12    = (const float*)d_in[20];
    const float* W_fout   = (const float*)d_in[21];
    const float* W_fe12   = (const float*)d_in[22];
    const float* W_feout  = (const float*)d_in[23];

    const int* src = eidx;
    const int* tgt = eidx + E;

    float* outN = (float*)d_out;
    float* outE = (float*)d_out + (size_t)Nn * 256;   // also holds edge_attr_e (prev_edge_attr)

    // ---- persistent workspace (~42 MB) ----
    char* W = (char*)d_ws;
    size_t off = 0;
    auto alloc = [&](size_t bytes) -> size_t {
        size_t o = off; off += (bytes + 255) & ~(size_t)255; return o;
    };
    float*    alpha = (float*)(W + alloc((size_t)E * 8 * 4));
    unsigned* amaxU = (unsigned*)(W + alloc((size_t)Nn * 8 * 4));
    float*    den   = (float*)(W + alloc((size_t)Nn * 8 * 4));
    float*    hat   = (float*)(W + alloc((size_t)Nn * 256 * 4));
    u16*      qkvb  = (u16*)(W + alloc((size_t)Nn * 768 * 2));
    u16*      sth   = (u16*)(W + alloc((size_t)Nn * 256 * 2));   // silu(t_emb_h) bf16
    // bf16 transposed weights
    u16* w1t    = (u16*)(W + alloc((size_t)256 * 256 * 2));
    u16* w2t    = (u16*)(W + alloc((size_t)256 * 128 * 2));
    u16* wadt   = (u16*)(W + alloc((size_t)1536 * 256 * 2));
    u16* wadet  = (u16*)(W + alloc((size_t)1536 * 256 * 2));
    u16* wqkvt  = (u16*)(W + alloc((size_t)768 * 256 * 2));
    u16* we0t   = (u16*)(W + alloc((size_t)256 * 256 * 2));
    u16* we1t   = (u16*)(W + alloc((size_t)256 * 256 * 2));
    u16* wn2et  = (u16*)(W + alloc((size_t)256 * 256 * 2));
    u16* wf12t  = (u16*)(W + alloc((size_t)2048 * 256 * 2));
    u16* wfoutt = (u16*)(W + alloc((size_t)256 * 1024 * 2));
    u16* wfe12t = (u16*)(W + alloc((size_t)2048 * 256 * 2));
    u16* wfeoutt= (u16*)(W + alloc((size_t)256 * 1024 * 2));

    char* pool = W + off;
    size_t poolB = (ws_size > off) ? (ws_size - off) : 0;
    auto chunkRowsB = [&](size_t bytesPerRow, int total) -> int {
        long c = (long)(poolB / bytesPerRow);
        c = (c / 256) * 256;
        if (c < 256) c = 256;
        if (c > total) c = (long)total;
        return (int)c;
    };

    hipMemsetAsync(amaxU, 0, (size_t)Nn * 8 * 4, stream);
    hipMemsetAsync(den, 0, (size_t)Nn * 8 * 4, stream);
    hipMemsetAsync(hat, 0, (size_t)Nn * 256 * 4, stream);

    // ---- weight conversion (transpose to N x K bf16) ----
    {
        struct WC { const float* w; u16* wt; int K, N; } wl[] = {
            { W_ee,             w1t,    256, 256 },
            { W_ee + 256 * 256, w2t,    128, 256 },
            { W_ad,             wadt,   256, 1536 },
            { W_ade,            wadet,  256, 1536 },
            { W_qkv,            wqkvt,  256, 768 },
            { W_e0,             we0t,   256, 256 },
            { W_e1,             we1t,   256, 256 },
            { W_n2e,            wn2et,  256, 256 },
            { W_f12,            wf12t,  256, 2048 },
            { W_fout,           wfoutt, 1024, 256 },
            { W_fe12,           wfe12t, 256, 2048 },
            { W_feout,          wfeoutt,1024, 256 },
        };
        for (auto& e : wl) {
            int cnt = e.K * e.N;
            hipLaunchKernelGGL(k_wconv, dim3((cnt + 255) / 256), dim3(256), 0, stream,
                               e.w, e.wt, e.K, e.N);
        }
    }

    // silu(t_emb_h) -> bf16 (persistent, reused phase 1 & 5)
    hipLaunchKernelGGL(k_silu_b16, dim3((unsigned)(((long long)Nn * 64 + 255) / 256)), dim3(256),
                       0, stream, t_emb_h, sth, (long long)Nn * 64);

    // ---- phase 1: node pre ----
    {
        int C = chunkRowsB(2048 + 512, Nn);
        float* msc = (float*)pool;
        u16*   xmc = (u16*)(pool + (size_t)C * 2048);
        for (int s = 0; s < Nn; s += C) {
            int cc = (Nn - s < C) ? (Nn - s) : C;
            gemm(stream, sth + (size_t)s * 256, 256, wadt, 256, msc, 512,
                 cc, 512, 256, b_ad, 0, 0, 0);
            hipLaunchKernelGGL(k_ln_mod_b16, dim3((cc + 3) / 4), dim3(256), 0, stream,
                               x + (size_t)s * 256, xmc, cc, msc, 512, 0, 256);
            gemm(stream, xmc, 256, wqkvt, 256, qkvb + (size_t)s * 768, 768,
                 cc, 768, 256, nullptr, 0, 0, 1);
        }
    }

    // ---- phase 2: edge pre: eae -> outE; e_mod; ea = gelu(e_mod@W_e0); alpha ----
    {
        int C = chunkRowsB(512 + 512 + 256 + 2048 + 512 + 1024, E);
        char* p = pool;
        u16*   ste   = (u16*)p;   p += (size_t)C * 512;
        u16*   eab   = (u16*)p;   p += (size_t)C * 512;
        u16*   distb = (u16*)p;   p += (size_t)C * 256;
        float* ems   = (float*)p; p += (size_t)C * 2048;
        u16*   emod  = (u16*)p;   p += (size_t)C * 512;
        float* eaf   = (float*)p;
        for (int s = 0; s < E; s += C) {
            int cc = (E - s < C) ? (E - s) : C;
            float* eaeC = outE + (size_t)s * 256;
            hipLaunchKernelGGL(k_silu_b16, dim3((unsigned)(((long long)cc * 64 + 255) / 256)),
                               dim3(256), 0, stream, t_emb_e + (size_t)s * 256, ste, (long long)cc * 64);
            hipLaunchKernelGGL(k_f2b4, dim3((unsigned)(((long long)cc * 64 + 255) / 256)),
                               dim3(256), 0, stream, edge_attr + (size_t)s * 256, eab, (long long)cc * 64);
            hipLaunchKernelGGL(k_f2b4, dim3((unsigned)(((long long)cc * 32 + 255) / 256)),
                               dim3(256), 0, stream, dist + (size_t)s * 128, distb, (long long)cc * 32);
            gemm(stream, eab, 256, w1t, 256, eaeC, 256, cc, 256, 256, b_ee, 0, 0, 0);
            gemm(stream, distb, 128, w2t, 128, eaeC, 256, cc, 256, 128, nullptr, 0, 1, 0);
            gemm(stream, ste, 256, wadet, 256, ems, 512, cc, 512, 256, b_ade, 0, 0, 0);
            hipLaunchKernelGGL(k_ln_mod_b16, dim3((cc + 3) / 4), dim3(256), 0, stream,
                               eaeC, emod, cc, ems, 512, 0, 256);
            gemm(stream, emod, 256, we0t, 256, eaf, 256, cc, 256, 256, nullptr, 2, 0, 0);
            hipLaunchKernelGGL(attn_alpha_k, dim3(cc), dim3(256), 0, stream,
                               qkvb, eaf, src + s, tgt + s, alpha + (size_t)s * 8, amaxU);
        }
    }

    // ---- phase 3: exp + denom ----
    hipLaunchKernelGGL(attn_exp_k, dim3((E * 8 + 255) / 256), dim3(256), 0, stream,
                       alpha, amaxU, den, tgt, E * 8);

    // ---- phase 4: message pass (recompute e_mod, e1) ----
    {
        int C = chunkRowsB(512 + 2048 + 512 + 1024, E);
        char* p = pool;
        u16*   ste  = (u16*)p;   p += (size_t)C * 512;
        float* ems  = (float*)p; p += (size_t)C * 2048;
        u16*   emod = (u16*)p;   p += (size_t)C * 512;
        float* e1f  = (float*)p;
        for (int s = 0; s < E; s += C) {
            int cc = (E - s < C) ? (E - s) : C;
            hipLaunchKernelGGL(k_silu_b16, dim3((unsigned)(((long long)cc * 64 + 255) / 256)),
                               dim3(256), 0, stream, t_emb_e + (size_t)s * 256, ste, (long long)cc * 64);
            gemm(stream, ste, 256, wadet, 256, ems, 512, cc, 512, 256, b_ade, 0, 0, 0);
            hipLaunchKernelGGL(k_ln_mod_b16, dim3((cc + 3) / 4), dim3(256), 0, stream,
                               outE + (size_t)s * 256, emod, cc, ems, 512, 0, 256);
            gemm(stream, emod, 256, we1t, 256, e1f, 256, cc, 256, 256, nullptr, 0, 0, 0);
            long long cnt = (long long)cc * 256;
            hipLaunchKernelGGL(attn_msg_k, dim3((unsigned)((cnt + 255) / 256)), dim3(256),
                               0, stream, qkvb, e1f, alpha + (size_t)s * 8, den, tgt + s,
                               hat, cnt);
        }
    }

    // ---- phase 5: node finish ----
    {
        int C = chunkRowsB(4096 + 512 + 4096 + 2048 + 1024, Nn);
        char* p = pool;
        float* ad2 = (float*)p; p += (size_t)C * 4096;
        u16*   h2  = (u16*)p;   p += (size_t)C * 512;
        u16*   h12 = (u16*)p;   p += (size_t)C * 4096;
        u16*   cb  = (u16*)p;   p += (size_t)C * 2048;
        float* fb  = (float*)p;
        for (int s = 0; s < Nn; s += C) {
            int cc = (Nn - s < C) ? (Nn - s) : C;
            gemm(stream, sth + (size_t)s * 256, 256, wadt + 512 * 256, 256, ad2, 1024,
                 cc, 1024, 256, b_ad + 512, 0, 0, 0);
            hipLaunchKernelGGL(k_ln_mod_resid_b16, dim3((cc + 3) / 4), dim3(256), 0, stream,
                               x + (size_t)s * 256, hat + (size_t)s * 256, h2, cc,
                               ad2, 1024, 0, ad2, 1024, 256, 512, g_ln, b_ln);
            gemm(stream, h2, 256, wf12t, 256, h12, 2048, cc, 2048, 256, nullptr, 0, 0, 1);
            hipLaunchKernelGGL(k_swiglu_b16, dim3((unsigned)(((long long)cc * 256 + 255) / 256)),
                               dim3(256), 0, stream, h12, cb, (long long)cc * 256);
            gemm(stream, cb, 1024, wfoutt, 1024, fb, 256, cc, 256, 1024, nullptr, 0, 0, 0);
            hipLaunchKernelGGL(k_final, dim3((unsigned)(((long long)cc * 64 + 255) / 256)),
                               dim3(256), 0, stream, (const float*)nullptr, h2, fb,
                               ad2, 1024, 768, outN + (size_t)s * 256, (long long)cc * 64);
        }
    }

    // ---- phase 6: edge finish ----
    {
        int C = chunkRowsB(512 + 512 + 1024 + 4096 + 512 + 4096 + 2048 + 1024, E);
        char* p = pool;
        u16*   ste  = (u16*)p;   p += (size_t)C * 512;
        u16*   gsum = (u16*)p;   p += (size_t)C * 512;
        float* hep  = (float*)p; p += (size_t)C * 1024;
        float* em2  = (float*)p; p += (size_t)C * 4096;
        u16*   h2   = (u16*)p;   p += (size_t)C * 512;
        u16*   h12  = (u16*)p;   p += (size_t)C * 4096;
        u16*   cb   = (u16*)p;   p += (size_t)C * 2048;
        float* fb   = (float*)p;
        for (int s = 0; s < E; s += C) {
            int cc = (E - s < C) ? (E - s) : C;
            hipLaunchKernelGGL(k_silu_b16, dim3((unsigned)(((long long)cc * 64 + 255) / 256)),
                               dim3(256), 0, stream, t_emb_e + (size_t)s * 256, ste, (long long)cc * 64);
            hipLaunchKernelGGL(k_gsum_b16, dim3((unsigned)(((long long)cc * 64 + 255) / 256)),
                               dim3(256), 0, stream, hat, src + s, tgt + s, gsum, (long long)cc * 64);
            gemm(stream, gsum, 256, wn2et, 256, hep, 256, cc, 256, 256, b_n2e, 0, 0, 0);
            gemm(stream, ste, 256, wadet + 512 * 256, 256, em2, 1024, cc, 1024, 256,
                 b_ade + 512, 0, 0, 0);
            hipLaunchKernelGGL(k_ln_mod_resid_b16, dim3((cc + 3) / 4), dim3(256), 0, stream,
                               edge_attr + (size_t)s * 256, hep, h2, cc,
                               em2, 1024, 0, em2, 1024, 256, 512, nullptr, nullptr);
            gemm(stream, h2, 256, wfe12t, 256, h12, 2048, cc, 2048, 256, nullptr, 0, 0, 1);
            hipLaunchKernelGGL(k_swiglu_b16, dim3((unsigned)(((long long)cc * 256 + 255) / 256)),
                               dim3(256), 0, stream, h12, cb, (long long)cc * 256);
            gemm(stream, cb, 1024, wfeoutt, 1024, fb, 256, cc, 256, 1024, nullptr, 0, 0, 0);
            hipLaunchKernelGGL(k_final, dim3((unsigned)(((long long)cc * 64 + 255) / 256)),
                               dim3(256), 0, stream, outE + (size_t)s * 256, h2, fb,
                               em2, 1024, 768, outE + (size_t)s * 256, (long long)cc * 64);
        }
    }
    (void)n_in; (void)out_size;
}

// Round 5
// 2526.566 us; speedup vs baseline: 3.8819x; 1.3321x over previous
//
#include <hip/hip_runtime.h>

#define HID 256

typedef unsigned short u16;
typedef __attribute__((ext_vector_type(8))) short bf16x8;
typedef __attribute__((ext_vector_type(4))) float f32x4;

__device__ __forceinline__ float siluf(float x) { return x / (1.f + __expf(-x)); }
__device__ __forceinline__ float geluf(float x) {
    return 0.5f * x * (1.f + tanhf(0.7978845608028654f * (x + 0.044715f * x * x * x)));
}
__device__ __forceinline__ u16 f2b(float x) {
    unsigned u = __float_as_uint(x);
    unsigned r = u + 0x7FFFu + ((u >> 16) & 1u);
    return (u16)(r >> 16);
}
__device__ __forceinline__ float b2f(u16 h) {
    return __uint_as_float(((unsigned)h) << 16);
}
__device__ __forceinline__ void gload16(const u16* g, u16* l) {
    __builtin_amdgcn_global_load_lds(
        (const __attribute__((address_space(1))) unsigned int*)g,
        (__attribute__((address_space(3))) unsigned int*)l, 16, 0, 0);
}
__device__ __forceinline__ int imin(int a, int b) { return a < b ? a : b; }

// ---------------- bf16 MFMA GEMM: C = act(A @ Bt^T + bias) ------------------------------
// A: M x K bf16 (lda). Bt: N x K bf16 (ldb). 128x128 tile, BK=32, 4 waves 2x2.
// obf16: LDS-repack epilogue with full-line stores. N%128==0, K%32==0.
__global__ __launch_bounds__(256) void gemm_mfma(
    const u16* __restrict__ A, int lda,
    const u16* __restrict__ Bt, int ldb,
    void* __restrict__ Cv, int ldc,
    int M, int N, int K,
    const float* __restrict__ bias, int act, int obf16)
{
    __shared__ u16 sm[8192 + 16384];   // stage A[128][32],B[128][32] + repack [128][128]
    u16* lds = sm;
    u16* rep = sm + 8192;

    const int tid  = threadIdx.x;
    const int lane = tid & 63;
    const int wave = tid >> 6;
    const int row0 = blockIdx.y * 128;
    const int col0 = blockIdx.x * 128;
    const int wm   = (wave >> 1) * 64;
    const int wn   = (wave & 1) * 64;

    f32x4 acc[4][4];
#pragma unroll
    for (int i = 0; i < 4; ++i)
#pragma unroll
        for (int j = 0; j < 4; ++j) acc[i][j] = (f32x4)0.0f;

    const int c0 = wave, c1 = wave + 4;
    const int r0 = c0 * 16 + (lane >> 2), r1 = c1 * 16 + (lane >> 2);
    const int kc = (lane & 3) * 8;
    const u16* pa0 = A + (size_t)imin(row0 + r0, M - 1) * lda + kc;
    const u16* pa1 = A + (size_t)imin(row0 + r1, M - 1) * lda + kc;
    const u16* pb0 = Bt + (size_t)(col0 + r0) * ldb + kc;
    const u16* pb1 = Bt + (size_t)(col0 + r1) * ldb + kc;
    u16* la0 = &lds[c0 * 512];
    u16* la1 = &lds[c1 * 512];
    u16* lb0 = &lds[4096 + c0 * 512];
    u16* lb1 = &lds[4096 + c1 * 512];

    const int kb = (lane >> 4) * 8;
    const int fr = lane & 15;

    for (int k0 = 0; k0 < K; k0 += 32) {
        gload16(pa0 + k0, la0);
        gload16(pa1 + k0, la1);
        gload16(pb0 + k0, lb0);
        gload16(pb1 + k0, lb1);
        __syncthreads();

        bf16x8 af[4], bfm[4];
#pragma unroll
        for (int i = 0; i < 4; ++i)
            af[i] = *(const bf16x8*)&lds[(wm + i * 16 + fr) * 32 + kb];
#pragma unroll
        for (int j = 0; j < 4; ++j)
            bfm[j] = *(const bf16x8*)&lds[4096 + (wn + j * 16 + fr) * 32 + kb];
#pragma unroll
        for (int i = 0; i < 4; ++i)
#pragma unroll
            for (int j = 0; j < 4; ++j)
                acc[i][j] = __builtin_amdgcn_mfma_f32_16x16x32_bf16(af[i], bfm[j], acc[i][j], 0, 0, 0);
        __syncthreads();
    }

    const int qr = (lane >> 4) * 4;
    if (obf16) {
#pragma unroll
        for (int i = 0; i < 4; ++i)
#pragma unroll
            for (int r = 0; r < 4; ++r)
#pragma unroll
                for (int j = 0; j < 4; ++j) {
                    int gcol = col0 + wn + j * 16 + fr;
                    float v = acc[i][j][r];
                    if (bias) v += bias[gcol];
                    if (act == 2) v = geluf(v);
                    else if (act == 1) v = siluf(v);
                    rep[(wm + i * 16 + qr + r) * 128 + wn + j * 16 + fr] = f2b(v);
                }
        __syncthreads();
        int row = tid >> 1, cc0 = (tid & 1) * 64;
        int grow = row0 + row;
        if (grow < M) {
            uint4* dst = (uint4*)((u16*)Cv + (size_t)grow * ldc + col0 + cc0);
            const uint4* sp = (const uint4*)&rep[row * 128 + cc0];
#pragma unroll
            for (int q = 0; q < 8; ++q) dst[q] = sp[q];   // 8 x 16B = 64 u16 (full span)
        }
    } else {
        float* Cf = (float*)Cv;
#pragma unroll
        for (int i = 0; i < 4; ++i)
#pragma unroll
            for (int r = 0; r < 4; ++r) {
                int grow = row0 + wm + i * 16 + qr + r;
                if (grow >= M) continue;
#pragma unroll
                for (int j = 0; j < 4; ++j) {
                    int gcol = col0 + wn + j * 16 + fr;
                    float v = acc[i][j][r];
                    if (bias) v += bias[gcol];
                    if (act == 2) v = geluf(v);
                    else if (act == 1) v = siluf(v);
                    Cf[(size_t)grow * ldc + gcol] = v;
                }
            }
    }
}

// ---------------- fused FFN12 + swiglu: C[:,j] = silu(A@W12a_j) * (A@W12b_j) ------------
// A: M x 256 bf16. Wt: 2048 x 256 bf16 (rows 0..1023 = a-cols, 1024..2047 = b-cols).
// C: M x 1024 bf16. Tile 128 rows x 64 cols. grid = (16, ceil(M/128)).
__global__ __launch_bounds__(256) void gemm_ffn12(
    const u16* __restrict__ A, const u16* __restrict__ Wt,
    u16* __restrict__ C, int M)
{
    __shared__ u16 sm[4096 + 2048 + 2048 + 8192];
    u16* lsA = sm;            // [128][32]
    u16* lsB1 = sm + 4096;    // [64][32]
    u16* lsB2 = sm + 6144;    // [64][32]
    u16* lsC = sm + 8192;     // [128][64]

    const int tid  = threadIdx.x;
    const int lane = tid & 63;
    const int wave = tid >> 6;
    const int row0 = blockIdx.y * 128;
    const int col0 = blockIdx.x * 64;
    const int wm   = (wave >> 1) * 64;
    const int wn   = (wave & 1) * 32;

    f32x4 accA[4][2], accB[4][2];
#pragma unroll
    for (int i = 0; i < 4; ++i)
#pragma unroll
        for (int j = 0; j < 2; ++j) { accA[i][j] = (f32x4)0.0f; accB[i][j] = (f32x4)0.0f; }

    const int kc = (lane & 3) * 8;
    const int rA0 = wave * 16 + (lane >> 2), rA1 = (wave + 4) * 16 + (lane >> 2);
    const int rB  = wave * 16 + (lane >> 2);
    const u16* pa0 = A + (size_t)imin(row0 + rA0, M - 1) * 256 + kc;
    const u16* pa1 = A + (size_t)imin(row0 + rA1, M - 1) * 256 + kc;
    const u16* pb1 = Wt + (size_t)(col0 + rB) * 256 + kc;
    const u16* pb2 = Wt + (size_t)(1024 + col0 + rB) * 256 + kc;
    u16* la0 = &lsA[wave * 512];
    u16* la1 = &lsA[(wave + 4) * 512];
    u16* lb1 = &lsB1[wave * 512];
    u16* lb2 = &lsB2[wave * 512];

    const int kb = (lane >> 4) * 8;
    const int fr = lane & 15;

#pragma unroll 1
    for (int k0 = 0; k0 < 256; k0 += 32) {
        gload16(pa0 + k0, la0);
        gload16(pa1 + k0, la1);
        gload16(pb1 + k0, lb1);
        gload16(pb2 + k0, lb2);
        __syncthreads();

        bf16x8 af[4], b1f[2], b2f_[2];
#pragma unroll
        for (int i = 0; i < 4; ++i)
            af[i] = *(const bf16x8*)&lsA[(wm + i * 16 + fr) * 32 + kb];
#pragma unroll
        for (int j = 0; j < 2; ++j) {
            b1f[j] = *(const bf16x8*)&lsB1[(wn + j * 16 + fr) * 32 + kb];
            b2f_[j] = *(const bf16x8*)&lsB2[(wn + j * 16 + fr) * 32 + kb];
        }
#pragma unroll
        for (int i = 0; i < 4; ++i)
#pragma unroll
            for (int j = 0; j < 2; ++j) {
                accA[i][j] = __builtin_amdgcn_mfma_f32_16x16x32_bf16(af[i], b1f[j], accA[i][j], 0, 0, 0);
                accB[i][j] = __builtin_amdgcn_mfma_f32_16x16x32_bf16(af[i], b2f_[j], accB[i][j], 0, 0, 0);
            }
        __syncthreads();
    }

    const int qr = (lane >> 4) * 4;
#pragma unroll
    for (int i = 0; i < 4; ++i)
#pragma unroll
        for (int r = 0; r < 4; ++r)
#pragma unroll
            for (int j = 0; j < 2; ++j) {
                float a = accA[i][j][r], b = accB[i][j][r];
                lsC[(wm + i * 16 + qr + r) * 64 + wn + j * 16 + fr] = f2b(siluf(a) * b);
            }
    __syncthreads();
    int row = tid >> 1, cc0 = (tid & 1) * 32;
    int grow = row0 + row;
    if (grow < M) {
        uint4* dst = (uint4*)(C + (size_t)grow * 1024 + col0 + cc0);
        const uint4* sp = (const uint4*)&lsC[row * 64 + cc0];
        dst[0] = sp[0]; dst[1] = sp[1]; dst[2] = sp[2]; dst[3] = sp[3];
    }
}

// ---------------- fused FFN-out + final: out = [eae+] h2 + gate*(A@Wout) ---------------
// A: M x 1024 bf16. Bt: 256 x 1024 bf16. out: M x 256 fp32. grid = (2, ceil(M/128)).
__global__ __launch_bounds__(256) void gemm_out_final(
    const u16* __restrict__ A, const u16* __restrict__ Bt,
    const float* __restrict__ eae, const u16* __restrict__ h2,
    const u16* __restrict__ gate, int ldg, int goff,
    float* __restrict__ out, int M)
{
    __shared__ u16 lds[8192];

    const int tid  = threadIdx.x;
    const int lane = tid & 63;
    const int wave = tid >> 6;
    const int row0 = blockIdx.y * 128;
    const int col0 = blockIdx.x * 128;
    const int wm   = (wave >> 1) * 64;
    const int wn   = (wave & 1) * 64;

    f32x4 acc[4][4];
#pragma unroll
    for (int i = 0; i < 4; ++i)
#pragma unroll
        for (int j = 0; j < 4; ++j) acc[i][j] = (f32x4)0.0f;

    const int c0 = wave, c1 = wave + 4;
    const int r0 = c0 * 16 + (lane >> 2), r1 = c1 * 16 + (lane >> 2);
    const int kc = (lane & 3) * 8;
    const u16* pa0 = A + (size_t)imin(row0 + r0, M - 1) * 1024 + kc;
    const u16* pa1 = A + (size_t)imin(row0 + r1, M - 1) * 1024 + kc;
    const u16* pb0 = Bt + (size_t)(col0 + r0) * 1024 + kc;
    const u16* pb1 = Bt + (size_t)(col0 + r1) * 1024 + kc;
    u16* la0 = &lds[c0 * 512];
    u16* la1 = &lds[c1 * 512];
    u16* lb0 = &lds[4096 + c0 * 512];
    u16* lb1 = &lds[4096 + c1 * 512];

    const int kb = (lane >> 4) * 8;
    const int fr = lane & 15;

    for (int k0 = 0; k0 < 1024; k0 += 32) {
        gload16(pa0 + k0, la0);
        gload16(pa1 + k0, la1);
        gload16(pb0 + k0, lb0);
        gload16(pb1 + k0, lb1);
        __syncthreads();

        bf16x8 af[4], bfm[4];
#pragma unroll
        for (int i = 0; i < 4; ++i)
            af[i] = *(const bf16x8*)&lds[(wm + i * 16 + fr) * 32 + kb];
#pragma unroll
        for (int j = 0; j < 4; ++j)
            bfm[j] = *(const bf16x8*)&lds[4096 + (wn + j * 16 + fr) * 32 + kb];
#pragma unroll
        for (int i = 0; i < 4; ++i)
#pragma unroll
            for (int j = 0; j < 4; ++j)
                acc[i][j] = __builtin_amdgcn_mfma_f32_16x16x32_bf16(af[i], bfm[j], acc[i][j], 0, 0, 0);
        __syncthreads();
    }

    const int qr = (lane >> 4) * 4;
#pragma unroll
    for (int i = 0; i < 4; ++i)
#pragma unroll
        for (int r = 0; r < 4; ++r) {
            int grow = row0 + wm + i * 16 + qr + r;
            if (grow >= M) continue;
#pragma unroll
            for (int j = 0; j < 4; ++j) {
                int gcol = col0 + wn + j * 16 + fr;
                size_t idx = (size_t)grow * 256 + gcol;
                float v = acc[i][j][r] * b2f(gate[(size_t)grow * ldg + goff + gcol]) + b2f(h2[idx]);
                if (eae) v += eae[idx];
                out[idx] = v;
            }
        }
}

// ---------------- weight transpose-convert: Wt[n*K+k] = bf16(W[k*N+n]) ------------------
__global__ __launch_bounds__(256) void k_wconv(
    const float* __restrict__ W, u16* __restrict__ Wt, int K, int N)
{
    int i = blockIdx.x * 256 + threadIdx.x;
    if (i >= K * N) return;
    int n = i / K, k = i - n * K;
    Wt[i] = f2b(W[(size_t)k * N + n]);
}

// ---------------- elementwise converters -----------------------------------------------
__global__ __launch_bounds__(256) void k_silu_b16(
    const float* __restrict__ src, u16* __restrict__ dst, long long n4)
{
    long long i = (long long)blockIdx.x * 256 + threadIdx.x;
    if (i >= n4) return;
    float4 v = ((const float4*)src)[i];
    ushort4 o;
    o.x = f2b(siluf(v.x)); o.y = f2b(siluf(v.y)); o.z = f2b(siluf(v.z)); o.w = f2b(siluf(v.w));
    ((ushort4*)dst)[i] = o;
}

// pack [edge_attr(256) | dist(128)] -> bf16 rows of 384
__global__ __launch_bounds__(256) void k_pack_ed(
    const float* __restrict__ ea_, const float* __restrict__ dist,
    u16* __restrict__ out, long long cnt4)
{
    long long i = (long long)blockIdx.x * 256 + threadIdx.x;
    if (i >= cnt4) return;
    long long r = i / 96;
    int c4 = (int)(i - r * 96) * 4;
    float4 v = (c4 < 256) ? *(const float4*)(ea_ + r * 256 + c4)
                          : *(const float4*)(dist + r * 128 + (c4 - 256));
    ushort4 o;
    o.x = f2b(v.x); o.y = f2b(v.y); o.z = f2b(v.z); o.w = f2b(v.w);
    *(ushort4*)(out + r * 384 + c4) = o;
}

// ---------------- LN + modulate (bf16 shift/scale) -> bf16 ------------------------------
__global__ __launch_bounds__(256) void k_ln_mod_b16(
    const float* __restrict__ X, u16* __restrict__ Y, int M,
    const u16* __restrict__ ssb, int ldss, int shoff, int scoff)
{
    int row = (blockIdx.x << 2) + (threadIdx.x >> 6);
    if (row >= M) return;
    int lane = threadIdx.x & 63;
    const float* xr = X + (size_t)row * HID + lane * 4;
    float x0 = xr[0], x1 = xr[1], x2 = xr[2], x3 = xr[3];
    float s = x0 + x1 + x2 + x3;
    float q = x0 * x0 + x1 * x1 + x2 * x2 + x3 * x3;
#pragma unroll
    for (int o = 32; o; o >>= 1) { s += __shfl_xor(s, o, 64); q += __shfl_xor(q, o, 64); }
    float m = s * (1.f / HID);
    float r = rsqrtf(q * (1.f / HID) - m * m + 1e-6f);
    const u16* sp = ssb + (size_t)row * ldss;
    ushort4 sh = *(const ushort4*)(sp + shoff + lane * 4);
    ushort4 sc = *(const ushort4*)(sp + scoff + lane * 4);
    ushort4 o;
    o.x = f2b((x0 - m) * r * (1.f + b2f(sc.x)) + b2f(sh.x));
    o.y = f2b((x1 - m) * r * (1.f + b2f(sc.y)) + b2f(sh.y));
    o.z = f2b((x2 - m) * r * (1.f + b2f(sc.z)) + b2f(sh.z));
    o.w = f2b((x3 - m) * r * (1.f + b2f(sc.w)) + b2f(sh.w));
    ((ushort4*)(Y + (size_t)row * HID))[lane] = o;
}

// ----- Y(bf16) = modulate( ln(A + gate.*Bv) [*g + b], shift, scale ); gate/ss bf16 ------
__global__ __launch_bounds__(256) void k_ln_mod_resid_b16(
    const float* __restrict__ A, const float* __restrict__ Bv, u16* __restrict__ Y, int M,
    const u16* __restrict__ gb, int ldg, int goff,
    const u16* __restrict__ ssb, int ldss, int shoff, int scoff,
    const float* __restrict__ gw, const float* __restrict__ bw)
{
    int row = (blockIdx.x << 2) + (threadIdx.x >> 6);
    if (row >= M) return;
    int lane = threadIdx.x & 63;
    const float* ar = A + (size_t)row * HID + lane * 4;
    const float* br = Bv + (size_t)row * HID + lane * 4;
    ushort4 gp = *(const ushort4*)(gb + (size_t)row * ldg + goff + lane * 4);
    float t0 = ar[0] + b2f(gp.x) * br[0];
    float t1 = ar[1] + b2f(gp.y) * br[1];
    float t2 = ar[2] + b2f(gp.z) * br[2];
    float t3 = ar[3] + b2f(gp.w) * br[3];
    float s = t0 + t1 + t2 + t3;
    float q = t0 * t0 + t1 * t1 + t2 * t2 + t3 * t3;
#pragma unroll
    for (int o = 32; o; o >>= 1) { s += __shfl_xor(s, o, 64); q += __shfl_xor(q, o, 64); }
    float m = s * (1.f / HID);
    float r = rsqrtf(q * (1.f / HID) - m * m + 1e-6f);
    float n0 = (t0 - m) * r, n1 = (t1 - m) * r, n2 = (t2 - m) * r, n3 = (t3 - m) * r;
    if (gw) {
        const float* g4 = gw + lane * 4;
        const float* b4 = bw + lane * 4;
        n0 = n0 * g4[0] + b4[0]; n1 = n1 * g4[1] + b4[1];
        n2 = n2 * g4[2] + b4[2]; n3 = n3 * g4[3] + b4[3];
    }
    const u16* sp = ssb + (size_t)row * ldss;
    ushort4 sh = *(const ushort4*)(sp + shoff + lane * 4);
    ushort4 sc = *(const ushort4*)(sp + scoff + lane * 4);
    ushort4 o;
    o.x = f2b(n0 * (1.f + b2f(sc.x)) + b2f(sh.x));
    o.y = f2b(n1 * (1.f + b2f(sc.y)) + b2f(sh.y));
    o.z = f2b(n2 * (1.f + b2f(sc.z)) + b2f(sh.z));
    o.w = f2b(n3 * (1.f + b2f(sc.w)) + b2f(sh.w));
    ((ushort4*)(Y + (size_t)row * HID))[lane] = o;
}

// ---------------- attention ------------------------------------------------------------
__device__ __forceinline__ unsigned fkey(float f) {
    unsigned u = __float_as_uint(f);
    return (u & 0x80000000u) ? ~u : (u | 0x80000000u);
}
__device__ __forceinline__ float funkey(unsigned k) {
    return (k & 0x80000000u) ? __uint_as_float(k & 0x7FFFFFFFu) : __uint_as_float(~k);
}

__global__ __launch_bounds__(256) void attn_alpha_k(
    const u16* __restrict__ qkv, const u16* __restrict__ ea,
    const int* __restrict__ src, const int* __restrict__ tgt,
    float* __restrict__ alpha, unsigned* __restrict__ amaxU)
{
    int e = blockIdx.x;
    int t = threadIdx.x;
    int h = t >> 5, d = t & 31;
    int s = src[e], g = tgt[e];
    float qv = b2f(qkv[(size_t)s * 768 + h * 32 + d]);
    float kv = b2f(qkv[(size_t)g * 768 + 256 + h * 32 + d]);
    float wv = b2f(ea[(size_t)e * 256 + t]);
    float v = qv * kv * wv;
#pragma unroll
    for (int o = 16; o; o >>= 1) v += __shfl_xor(v, o, 32);
    if (d == 0) {
        float a = v * 0.17677669529663687f;  // 1/sqrt(32)
        alpha[(size_t)e * 8 + h] = a;
        atomicMax(&amaxU[(size_t)g * 8 + h], fkey(a));
    }
}

__global__ __launch_bounds__(256) void attn_exp_k(
    float* __restrict__ alpha, const unsigned* __restrict__ amaxU,
    float* __restrict__ denom, const int* __restrict__ tgt, int EH)
{
    int i = blockIdx.x * 256 + threadIdx.x;
    if (i >= EH) return;
    int e = i >> 3, h = i & 7;
    int g = tgt[e];
    float m = funkey(amaxU[(size_t)g * 8 + h]);
    float ex = __expf(alpha[i] - m);
    alpha[i] = ex;
    atomicAdd(&denom[(size_t)g * 8 + h], ex);
}

__global__ __launch_bounds__(256) void attn_msg_k(
    const u16* __restrict__ qkv, const u16* __restrict__ e1,
    const float* __restrict__ alpha, const float* __restrict__ denom,
    const int* __restrict__ tgt, float* __restrict__ hattn, long long EC)
{
    long long i = (long long)blockIdx.x * 256 + threadIdx.x;
    if (i >= EC) return;
    long long e = i >> 8;
    int c = (int)(i & 255);
    int h = c >> 5;
    int g = tgt[e];
    float w = alpha[e * 8 + h] / denom[(size_t)g * 8 + h];
    float val = b2f(qkv[(size_t)g * 768 + 512 + c]) * b2f(e1[i]) * w;
    atomicAdd(&hattn[(size_t)g * 256 + c], val);
}

// ---------------- gsum -----------------------------------------------------------------
__global__ __launch_bounds__(256) void k_gsum_b16(
    const float* __restrict__ hattn, const int* __restrict__ src, const int* __restrict__ tgt,
    u16* __restrict__ g, long long cnt4)
{
    long long i = (long long)blockIdx.x * 256 + threadIdx.x;
    if (i >= cnt4) return;
    long long e = i >> 6;
    int c4 = (int)(i & 63) * 4;
    float4 a = *(const float4*)(hattn + (size_t)src[e] * 256 + c4);
    float4 b = *(const float4*)(hattn + (size_t)tgt[e] * 256 + c4);
    ushort4 o;
    o.x = f2b(a.x + b.x); o.y = f2b(a.y + b.y); o.z = f2b(a.z + b.z); o.w = f2b(a.w + b.w);
    ((ushort4*)g)[i] = o;
}

// ---------------------------------------------------------------------------------------
static inline void gemm(hipStream_t st, const u16* A, int lda, const u16* Bt, int ldb,
                        void* C, int ldc, int M, int N, int K,
                        const float* bias, int act, int obf16)
{
    dim3 g(N / 128, (M + 127) / 128);
    hipLaunchKernelGGL(gemm_mfma, g, dim3(256), 0, st, A, lda, Bt, ldb, C, ldc, M, N, K,
                       bias, act, obf16);
}

extern "C" void kernel_launch(void* const* d_in, const int* in_sizes, int n_in,
                              void* d_out, int out_size, void* d_ws, size_t ws_size,
                              hipStream_t stream)
{
    const int Nn = in_sizes[0];
    const int E = in_sizes[3] / HID;

    const float* x        = (const float*)d_in[1];
    const float* t_emb_h  = (const float*)d_in[2];
    const float* edge_attr= (const float*)d_in[3];
    const int*   eidx     = (const int*)d_in[4];
    const float* t_emb_e  = (const float*)d_in[5];
    const float* dist     = (const float*)d_in[6];
    const float* W_ee     = (const float*)d_in[7];
    const float* b_ee     = (const float*)d_in[8];
    const float* W_ad     = (const float*)d_in[9];
    const float* b_ad     = (const float*)d_in[10];
    const float* W_ade    = (const float*)d_in[11];
    const float* b_ade    = (const float*)d_in[12];
    const float* W_qkv    = (const float*)d_in[13];
    const float* W_e0     = (const float*)d_in[14];
    const float* W_e1     = (const float*)d_in[15];
    const float* W_n2e    = (const float*)d_in[16];
    const float* b_n2e    = (const float*)d_in[17];
    const float* g_ln     = (const float*)d_in[18];
    const float* b_ln     = (const float*)d_in[19];
    const float* W_f12    = (const float*)d_in[20];
    const float* W_fout   = (const float*)d_in[21];
    const float* W_fe12   = (const float*)d_in[22];
    const float* W_feout  = (const float*)d_in[23];

    const int* src = eidx;
    const int* tgt = eidx + E;

    float* outN = (float*)d_out;
    float* outE = (float*)d_out + (size_t)Nn * 256;   // also holds edge_attr_e (prev_edge_attr)

    // ---- persistent workspace ----
    char* W = (char*)d_ws;
    size_t off = 0;
    auto alloc = [&](size_t bytes) -> size_t {
        size_t o = off; off += (bytes + 255) & ~(size_t)255; return o;
    };
    float*    alpha = (float*)(W + alloc((size_t)E * 8 * 4));
    unsigned* amaxU = (unsigned*)(W + alloc((size_t)Nn * 8 * 4));
    float*    den   = (float*)(W + alloc((size_t)Nn * 8 * 4));
    float*    hat   = (float*)(W + alloc((size_t)Nn * 256 * 4));
    u16*      qkvb  = (u16*)(W + alloc((size_t)Nn * 768 * 2));
    u16*      sth   = (u16*)(W + alloc((size_t)Nn * 256 * 2));
    u16*      steb  = (u16*)(W + alloc((size_t)E * 256 * 2));    // silu(t_emb_e)
    u16*      e1b   = (u16*)(W + alloc((size_t)E * 256 * 2));    // e_mod @ W_e1
    u16*      adnb  = (u16*)(W + alloc((size_t)Nn * 1536 * 2));  // full node adaln
    u16*      xmb   = (u16*)(W + alloc((size_t)Nn * 256 * 2));
    u16*      h2nb  = (u16*)(W + alloc((size_t)Nn * 256 * 2));
    u16*      cnb   = (u16*)(W + alloc((size_t)Nn * 1024 * 2));
    // bf16 transposed weights (N x K)
    u16* weet   = (u16*)(W + alloc((size_t)256 * 384 * 2));
    u16* wadt   = (u16*)(W + alloc((size_t)1536 * 256 * 2));
    u16* wadet  = (u16*)(W + alloc((size_t)1536 * 256 * 2));
    u16* wqkvt  = (u16*)(W + alloc((size_t)768 * 256 * 2));
    u16* we0t   = (u16*)(W + alloc((size_t)256 * 256 * 2));
    u16* we1t   = (u16*)(W + alloc((size_t)256 * 256 * 2));
    u16* wn2et  = (u16*)(W + alloc((size_t)256 * 256 * 2));
    u16* wf12t  = (u16*)(W + alloc((size_t)2048 * 256 * 2));
    u16* wfoutt = (u16*)(W + alloc((size_t)256 * 1024 * 2));
    u16* wfe12t = (u16*)(W + alloc((size_t)2048 * 256 * 2));
    u16* wfeoutt= (u16*)(W + alloc((size_t)256 * 1024 * 2));

    char* pool = W + off;
    size_t poolB = (ws_size > off) ? (ws_size - off) : 0;
    auto chunkRowsB = [&](size_t bytesPerRow, int total) -> int {
        long c = (long)(poolB / bytesPerRow);
        c = (c / 256) * 256;
        if (c < 256) c = 256;
        if (c > total) c = (long)total;
        return (int)c;
    };

    hipMemsetAsync(amaxU, 0, (size_t)Nn * 8 * 4, stream);
    hipMemsetAsync(den, 0, (size_t)Nn * 8 * 4, stream);
    hipMemsetAsync(hat, 0, (size_t)Nn * 256 * 4, stream);

    // ---- weight conversion ----
    {
        struct WC { const float* w; u16* wt; int K, N; } wl[] = {
            { W_ee,    weet,   384, 256 },
            { W_ad,    wadt,   256, 1536 },
            { W_ade,   wadet,  256, 1536 },
            { W_qkv,   wqkvt,  256, 768 },
            { W_e0,    we0t,   256, 256 },
            { W_e1,    we1t,   256, 256 },
            { W_n2e,   wn2et,  256, 256 },
            { W_f12,   wf12t,  256, 2048 },
            { W_fout,  wfoutt, 1024, 256 },
            { W_fe12,  wfe12t, 256, 2048 },
            { W_feout, wfeoutt,1024, 256 },
        };
        for (auto& e : wl) {
            int cnt = e.K * e.N;
            hipLaunchKernelGGL(k_wconv, dim3((cnt + 255) / 256), dim3(256), 0, stream,
                               e.w, e.wt, e.K, e.N);
        }
    }

    // silu conversions (persistent)
    hipLaunchKernelGGL(k_silu_b16, dim3((unsigned)(((long long)Nn * 64 + 255) / 256)), dim3(256),
                       0, stream, t_emb_h, sth, (long long)Nn * 64);
    hipLaunchKernelGGL(k_silu_b16, dim3((unsigned)(((long long)E * 64 + 255) / 256)), dim3(256),
                       0, stream, t_emb_e, steb, (long long)E * 64);

    // ---- phase 1: node pre (no chunking; buffers persistent) ----
    gemm(stream, sth, 256, wadt, 256, adnb, 1536, Nn, 1536, 256, b_ad, 0, 1);
    hipLaunchKernelGGL(k_ln_mod_b16, dim3((Nn + 3) / 4), dim3(256), 0, stream,
                       x, xmb, Nn, adnb, 1536, 0, 256);
    gemm(stream, xmb, 256, wqkvt, 256, qkvb, 768, Nn, 768, 256, nullptr, 0, 1);

    // ---- phase 2: edge pre ----
    {
        int C = chunkRowsB(768 + 1024 + 512 + 512, E);
        char* p = pool;
        u16* eab2 = (u16*)p; p += (size_t)C * 768;    // packed [edge_attr|dist] K=384
        u16* emsb = (u16*)p; p += (size_t)C * 1024;   // adaln_e[:,0:512)
        u16* emod = (u16*)p; p += (size_t)C * 512;
        u16* eam  = (u16*)p;                          // gelu(e_mod@W_e0)
        for (int s = 0; s < E; s += C) {
            int cc = (E - s < C) ? (E - s) : C;
            float* eaeC = outE + (size_t)s * 256;
            hipLaunchKernelGGL(k_pack_ed, dim3((unsigned)(((long long)cc * 96 + 255) / 256)),
                               dim3(256), 0, stream, edge_attr + (size_t)s * 256,
                               dist + (size_t)s * 128, eab2, (long long)cc * 96);
            gemm(stream, eab2, 384, weet, 384, eaeC, 256, cc, 256, 384, b_ee, 0, 0);
            gemm(stream, steb + (size_t)s * 256, 256, wadet, 256, emsb, 512, cc, 512, 256,
                 b_ade, 0, 1);
            hipLaunchKernelGGL(k_ln_mod_b16, dim3((cc + 3) / 4), dim3(256), 0, stream,
                               eaeC, emod, cc, emsb, 512, 0, 256);
            gemm(stream, emod, 256, we0t, 256, eam, 256, cc, 256, 256, nullptr, 2, 1);
            gemm(stream, emod, 256, we1t, 256, e1b + (size_t)s * 256, 256, cc, 256, 256,
                 nullptr, 0, 1);
            hipLaunchKernelGGL(attn_alpha_k, dim3(cc), dim3(256), 0, stream,
                               qkvb, eam, src + s, tgt + s, alpha + (size_t)s * 8, amaxU);
        }
    }

    // ---- phase 3: exp + denom ----
    hipLaunchKernelGGL(attn_exp_k, dim3((E * 8 + 255) / 256), dim3(256), 0, stream,
                       alpha, amaxU, den, tgt, E * 8);

    // ---- phase 4: message pass (e1 persisted) ----
    hipLaunchKernelGGL(attn_msg_k, dim3((unsigned)(((long long)E * 256 + 255) / 256)), dim3(256),
                       0, stream, qkvb, e1b, alpha, den, tgt, hat, (long long)E * 256);

    // ---- phase 5: node finish ----
    hipLaunchKernelGGL(k_ln_mod_resid_b16, dim3((Nn + 3) / 4), dim3(256), 0, stream,
                       x, hat, h2nb, Nn, adnb, 1536, 512, adnb, 1536, 768, 1024, g_ln, b_ln);
    hipLaunchKernelGGL(gemm_ffn12, dim3(16, (Nn + 127) / 128), dim3(256), 0, stream,
                       h2nb, wf12t, cnb, Nn);
    hipLaunchKernelGGL(gemm_out_final, dim3(2, (Nn + 127) / 128), dim3(256), 0, stream,
                       cnb, wfoutt, (const float*)nullptr, h2nb, adnb, 1536, 1280, outN, Nn);

    // ---- phase 6: edge finish ----
    {
        int C = chunkRowsB(512 + 2048 + 1024 + 512 + 2048, E);
        char* p = pool;
        u16*   gsum = (u16*)p;  p += (size_t)C * 512;
        u16*   em2b = (u16*)p;  p += (size_t)C * 2048;   // adaln_e[:,512:1536)
        float* hep  = (float*)p; p += (size_t)C * 1024;
        u16*   h2e  = (u16*)p;  p += (size_t)C * 512;
        u16*   cne  = (u16*)p;                            // swiglu out C x 1024
        for (int s = 0; s < E; s += C) {
            int cc = (E - s < C) ? (E - s) : C;
            hipLaunchKernelGGL(k_gsum_b16, dim3((unsigned)(((long long)cc * 64 + 255) / 256)),
                               dim3(256), 0, stream, hat, src + s, tgt + s, gsum, (long long)cc * 64);
            gemm(stream, gsum, 256, wn2et, 256, hep, 256, cc, 256, 256, b_n2e, 0, 0);
            gemm(stream, steb + (size_t)s * 256, 256, wadet + 512 * 256, 256, em2b, 1024,
                 cc, 1024, 256, b_ade + 512, 0, 1);
            hipLaunchKernelGGL(k_ln_mod_resid_b16, dim3((cc + 3) / 4), dim3(256), 0, stream,
                               edge_attr + (size_t)s * 256, hep, h2e, cc,
                               em2b, 1024, 0, em2b, 1024, 256, 512, nullptr, nullptr);
            hipLaunchKernelGGL(gemm_ffn12, dim3(16, (cc + 127) / 128), dim3(256), 0, stream,
                               h2e, wfe12t, cne, cc);
            hipLaunchKernelGGL(gemm_out_final, dim3(2, (cc + 127) / 128), dim3(256), 0, stream,
                               cne, wfeoutt, outE + (size_t)s * 256, h2e,
                               em2b, 1024, 768, outE + (size_t)s * 256, cc);
        }
    }
    (void)n_in; (void)out_size;
}